// Round 15
// baseline (217.045 us; speedup 1.0000x reference)
//
#include <hip/hip_runtime.h>

typedef unsigned short u16;
typedef unsigned int u32;
typedef __attribute__((ext_vector_type(8))) short bf16x8;
typedef __attribute__((ext_vector_type(4))) float f32x4;
typedef __attribute__((ext_vector_type(4))) u32 u32x4;

#define T_TOK 3072
#define HID 2048
#define NH 16
#define NKV 4
#define HD 128
#define QKVN 3072
#define ATT_SCALE 0.08838834764831845f
#define LOG2E 1.4426950408889634f
#define SCL2 (ATT_SCALE * LOG2E)

__device__ __forceinline__ u16 f2bf(float x) {
  u32 u = __builtin_bit_cast(u32, x);
  u = u + 0x7FFFu + ((u >> 16) & 1u);
  return (u16)(u >> 16);
}
__device__ __forceinline__ float bf2f(u16 h) {
  return __builtin_bit_cast(float, (u32)h << 16);
}
__device__ __forceinline__ u32 cvtpk(float lo, float hi) {
  u32 r;
  asm("v_cvt_pk_bf16_f32 %0, %1, %2" : "=v"(r) : "v"(lo), "v"(hi));
  return r;
}
__device__ __forceinline__ void gload16(const void* g, void* l) {
  __builtin_amdgcn_global_load_lds((const __attribute__((address_space(1))) void*)g,
                                   (__attribute__((address_space(3))) void*)l, 16, 0, 0);
}

// ---------------- fp32 -> bf16 convert, 3 regions in one launch ----------------
__global__ void k_cvt3(const float* __restrict__ s0p, u16* __restrict__ d0p, int n0,
                       const float* __restrict__ s1p, u16* __restrict__ d1p, int n1,
                       const float* __restrict__ s2p, u16* __restrict__ d2p, int n2) {
  const float* s;
  u16* d;
  int n, b = blockIdx.x, nb;
  if (b < 1024) {
    s = s0p; d = d0p; n = n0; nb = 1024;
  } else if (b < 2048) {
    s = s1p; d = d1p; n = n1; b -= 1024; nb = 1024;
  } else {
    s = s2p; d = d2p; n = n2; b -= 2048; nb = 512;
  }
  int i = (b * 256 + threadIdx.x) * 4;
  int stride = nb * 256 * 4;
  for (; i < n; i += stride) {
    float4 v = *(const float4*)(s + i);
    u32 lo = cvtpk(v.x, v.y);
    u32 hi = cvtpk(v.z, v.w);
    *(uint2*)(d + i) = make_uint2(lo, hi);
  }
}

// ---------------- 2-phase double-buffered GEMM: C = A * B^T ----------------
// (round-12 configuration — measured 42/28 µs)
template <int MR, int NR, bool OUT_BF16, bool VT_MODE>
__global__ __launch_bounds__(512) void k_gemm2p(const u16* __restrict__ A,
                                                const u16* __restrict__ B,
                                                void* __restrict__ Cp,
                                                u16* __restrict__ vt,
                                                int M, int N, int K) {
  constexpr int BM = 32 * MR;
  constexpr int BN = 64 * NR;
  __shared__ u16 Ash[2][BM * 64];
  __shared__ u16 Bsh[2][BN * 64];
  const int tid = threadIdx.x;
  const int wv = tid >> 6, ln = tid & 63;
  const int wr = wv >> 2, wc = wv & 3;
  const int g = ln >> 4, r16 = ln & 15;
  const int m0 = blockIdx.y * BM, n0 = blockIdx.x * BN;
  const int NT = K >> 6;
  const int srow = ln >> 3;                   // row within 8-row DMA block
  const int sswz = ((ln & 7) ^ srow) << 3;    // pre-swizzled source col (elems)
  const u16* Abase = A + (size_t)m0 * K;
  const u16* Bbase = B + (size_t)n0 * K;
  const int xorc = (r16 & 7) << 3;

  f32x4 acc[MR][NR] = {};

  auto stage = [&](int buf, int T) {
#pragma unroll
    for (int a = 0; a < BM / 64; ++a)
      gload16(Abase + (size_t)(a * 64 + wv * 8 + srow) * K + T * 64 + sswz,
              &Ash[buf][(a * 64 + wv * 8) * 64]);
#pragma unroll
    for (int b = 0; b < BN / 64; ++b)
      gload16(Bbase + (size_t)(b * 64 + wv * 8 + srow) * K + T * 64 + sswz,
              &Bsh[buf][(b * 64 + wv * 8) * 64]);
  };

  stage(0, 0);
  __syncthreads();
  int cur = 0;
  for (int T = 0; T < NT; ++T) {
    if (T + 1 < NT) stage(cur ^ 1, T + 1);
    const u16* As = Ash[cur];
    const u16* Bs = Bsh[cur];
#pragma unroll
    for (int kk = 0; kk < 2; ++kk) {
      const int ecol = (kk * 32 + g * 8) ^ xorc;
      bf16x8 af[MR], bfr[NR];
#pragma unroll
      for (int m = 0; m < MR; ++m)
        af[m] = *(const bf16x8*)&As[(wr * (MR * 16) + m * 16 + r16) * 64 + ecol];
#pragma unroll
      for (int n = 0; n < NR; ++n)
        bfr[n] = *(const bf16x8*)&Bs[(wc * (NR * 16) + n * 16 + r16) * 64 + ecol];
      __builtin_amdgcn_s_setprio(1);
#pragma unroll
      for (int m = 0; m < MR; ++m)
#pragma unroll
        for (int n = 0; n < NR; ++n)
          acc[m][n] = __builtin_amdgcn_mfma_f32_16x16x32_bf16(af[m], bfr[n], acc[m][n], 0, 0, 0);
      __builtin_amdgcn_s_setprio(0);
    }
    __syncthreads();
    cur ^= 1;
  }
  // ---- epilogue ----
#pragma unroll
  for (int n = 0; n < NR; ++n) {
    int col = n0 + wc * (NR * 16) + n * 16 + r16;
    bool tov = VT_MODE && (col >= 2560);
#pragma unroll
    for (int m = 0; m < MR; ++m) {
      int row = m0 + wr * (MR * 16) + m * 16 + g * 4;
      if (tov) {
        u32 lo2 = (u32)f2bf(acc[m][n][0]) | ((u32)f2bf(acc[m][n][1]) << 16);
        u32 hi2 = (u32)f2bf(acc[m][n][2]) | ((u32)f2bf(acc[m][n][3]) << 16);
        *(uint2*)&vt[(size_t)(col - 2560) * T_TOK + row] = make_uint2(lo2, hi2);
      } else {
#pragma unroll
        for (int j = 0; j < 4; ++j) {
          if (OUT_BF16)
            ((u16*)Cp)[(size_t)(row + j) * N + col] = f2bf(acc[m][n][j]);
          else
            ((float*)Cp)[(size_t)(row + j) * N + col] = acc[m][n][j];
        }
      }
    }
  }
}

// ---------------- RMSNorm + RoPE (in-place on bf16 qkv, Q and K only) ----------------
__global__ void k_normrope(u16* __restrict__ qkv, const float* __restrict__ cs,
                           const float* __restrict__ sn, const float* __restrict__ qw,
                           const float* __restrict__ kw) {
  int t = blockIdx.x;
  int idx = blockIdx.y * 4 + (threadIdx.x >> 6);  // 0..19
  int l = threadIdx.x & 63;
  bool isq = idx < NH;
  int off = isq ? idx * HD : HID + (idx - NH) * HD;
  u16* p = qkv + (size_t)t * QKVN + off;
  float x0 = bf2f(p[l]), x1 = bf2f(p[l + 64]);
  float ss = x0 * x0 + x1 * x1;
#pragma unroll
  for (int d = 1; d < 64; d <<= 1) ss += __shfl_xor(ss, d, 64);
  float rs = rsqrtf(ss * (1.0f / 128.0f) + 1e-6f);
  const float* w = isq ? qw : kw;
  float xn0 = x0 * rs * w[l];
  float xn1 = x1 * rs * w[l + 64];
  const float* ct = cs + (size_t)t * HD;
  const float* st = sn + (size_t)t * HD;
  float o0 = xn0 * ct[l] - xn1 * st[l];
  float o1 = xn1 * ct[l + 64] + xn0 * st[l + 64];
  p[l] = f2bf(o0);
  p[l + 64] = f2bf(o1);
}

// ---------------- GQA attention: s-split 8-wave blocks (2x TLP) ----------------
// Block = 512 thr = 8 waves = 4 heads x 2 s-halves. Wave (hw, sh) runs the
// round-12 flash loop on s-half [s0+32*sh, +32) with private (m,l,acc);
// halves merged at end via LDS overlay on the dead K/V buffers.
// LDS 33KB -> 3 blocks/CU = 24 waves/CU (vs round-12's 12).
__global__ __launch_bounds__(512, 6) void k_attn(const u16* __restrict__ qkv,
                                                 const u16* __restrict__ vt,
                                                 u16* __restrict__ attn) {
  __shared__ u16 smem[64 * 128 + 128 * 64];  // Ksh | Vsh; overlaid by Osc in merge
  __shared__ float msh[8][16], lsh[8][16];
  u16* Ksh = smem;               // [64][128], granule ^ (s&7)
  u16* Vsh = smem + 64 * 128;    // [128][64], granule ^ (d&7)
  const int id = blockIdx.x;
  const int xcd = id & 7, slot = id >> 3;              // slot 0..95
  const int hkv = xcd >> 1;                            // 2 XCDs per kv-group
  const int t0 = (191 - (slot * 2 + (xcd & 1))) * 16;  // reversed: long blocks first
  const int tid = threadIdx.x, wv = tid >> 6, ln = tid & 63;
  const int g = ln >> 4, r16 = ln & 15;
  const int hw = wv & 3;          // head within kv-group
  const int sh = wv >> 2;         // s-half 0/1
  const int h = hkv * 4 + hw;
  const int swz = r16 & 7;
  const bool ghi = (g >> 1) != 0;
  const int L0 = r16 + 16 * ((2 * g) & 3);   // src lanes for P-fragment shfl
  const int L1 = r16 + 16 * ((2 * g + 1) & 3);

  bf16x8 qf[4];
  const u16* qrow = qkv + (size_t)(t0 + r16) * QKVN + h * HD;
#pragma unroll
  for (int kk = 0; kk < 4; ++kk) qf[kk] = *(const bf16x8*)(qrow + kk * 32 + g * 8);

  float m_run = -1e30f, l_part = 0.f;   // row t = t0 + r16 (per-lane), this s-half
  f32x4 acc_o[8] = {};                  // rows t = t0+g*4+j, cols d = db*16+r16 (partial)

  const u16* Kbase = qkv + HID + hkv * HD;
  const u16* Vbase = vt + (size_t)(hkv * HD) * T_TOK;

  int lo = t0 - 1023;
  if (lo < 0) lo = 0;
  lo &= ~63;
  const int t_hi = t0 + 15;

  for (int s0 = lo; s0 <= t_hi; s0 += 64) {
    // ---- stage K [64][128] + V^T [128][64]; 4 DMAs per wave ----
#pragma unroll
    for (int ph = 0; ph < 2; ++ph) {
      int ks = wv * 8 + ph * 4 + (ln >> 4);
      int kc = (ln & 15) ^ (ks & 7);
      gload16(Kbase + (size_t)(s0 + ks) * QKVN + (kc << 3),
              &Ksh[(wv * 8 + ph * 4) * 128]);
      int vd = wv * 16 + ph * 8 + (ln >> 3);
      int vc = (ln & 7) ^ (vd & 7);
      gload16(Vbase + (size_t)vd * T_TOK + s0 + (vc << 3),
              &Vsh[(wv * 16 + ph * 8) * 64]);
    }
    __syncthreads();  // drains vmcnt(0): staged data visible

    const int sbase = s0 + sh * 32;
    // ---- S^T = K Q^T on this wave's s-half: 2 sb tiles ----
    f32x4 sc[2] = {};
    __builtin_amdgcn_s_setprio(1);
#pragma unroll
    for (int sb = 0; sb < 2; ++sb) {
#pragma unroll
      for (int kk = 0; kk < 4; ++kk) {
        const bf16x8 kf = *(const bf16x8*)
            &Ksh[(sh * 32 + sb * 16 + r16) * 128 + (((kk * 4 + g) ^ swz) << 3)];
        sc[sb] = __builtin_amdgcn_mfma_f32_16x16x32_bf16(kf, qf[kk], sc[sb], 0, 0, 0);
      }
    }
    __builtin_amdgcn_s_setprio(0);

    // ---- mask (exact per-tile-half conditions) + row max ----
    const bool mtile = (sbase > t0 - 28) || (sbase <= t0 - 1009);
    const int t = t0 + r16;
    float pmax = -__builtin_inff();
    if (mtile) {
#pragma unroll
      for (int sb = 0; sb < 2; ++sb)
#pragma unroll
        for (int j = 0; j < 4; ++j) {
          int s = sbase + sb * 16 + g * 4 + j;
          bool ok = (s <= (t | 3)) && (t - s < 1024);
          float x = ok ? sc[sb][j] : -__builtin_inff();
          sc[sb][j] = x;
          pmax = fmaxf(pmax, x);
        }
    } else {
#pragma unroll
      for (int sb = 0; sb < 2; ++sb)
#pragma unroll
        for (int j = 0; j < 4; ++j) pmax = fmaxf(pmax, sc[sb][j]);
    }
    pmax = fmaxf(pmax, __shfl_xor(pmax, 16, 64));
    pmax = fmaxf(pmax, __shfl_xor(pmax, 32, 64));

    // ---- defer-max online softmax (log2 domain) ----
    float needv = fmaf(pmax, SCL2, -m_run);
    if (!__all(needv <= 11.5f)) {
      float mnew = fmaxf(m_run, pmax * SCL2);
      float fac = exp2f(m_run - mnew);
      m_run = mnew;
      l_part *= fac;
      float fj[4];
#pragma unroll
      for (int j = 0; j < 4; ++j) fj[j] = __shfl(fac, (ln & 48) + g * 4 + j, 64);
#pragma unroll
      for (int db = 0; db < 8; ++db)
#pragma unroll
        for (int j = 0; j < 4; ++j) acc_o[db][j] *= fj[j];
    }
    const float nm = -m_run;
    u32 w0[2], w1[2];
#pragma unroll
    for (int sb = 0; sb < 2; ++sb) {
      float e0 = exp2f(fmaf(sc[sb][0], SCL2, nm));
      float e1 = exp2f(fmaf(sc[sb][1], SCL2, nm));
      float e2 = exp2f(fmaf(sc[sb][2], SCL2, nm));
      float e3 = exp2f(fmaf(sc[sb][3], SCL2, nm));
      l_part += (e0 + e1) + (e2 + e3);
      w0[sb] = cvtpk(e0, e1);
      w1[sb] = cvtpk(e2, e3);
    }

    // ---- O += P V on this s-half (P rearranged via shfl) ----
    __builtin_amdgcn_s_setprio(1);
    {
      u32 a0 = __shfl(w0[0], L0, 64), b0 = __shfl(w0[1], L0, 64);
      u32 a1 = __shfl(w1[0], L0, 64), b1 = __shfl(w1[1], L0, 64);
      u32 a2 = __shfl(w0[0], L1, 64), b2 = __shfl(w0[1], L1, 64);
      u32 a3 = __shfl(w1[0], L1, 64), b3 = __shfl(w1[1], L1, 64);
      u32x4 pw;
      pw[0] = ghi ? b0 : a0;
      pw[1] = ghi ? b1 : a1;
      pw[2] = ghi ? b2 : a2;
      pw[3] = ghi ? b3 : a3;
      const bf16x8 pa = __builtin_bit_cast(bf16x8, pw);
#pragma unroll
      for (int db = 0; db < 8; ++db) {
        const bf16x8 vb = *(const bf16x8*)
            &Vsh[(db * 16 + r16) * 64 + (((sh * 4 + g) ^ swz) << 3)];
        acc_o[db] = __builtin_amdgcn_mfma_f32_16x16x32_bf16(pa, vb, acc_o[db], 0, 0, 0);
      }
    }
    __builtin_amdgcn_s_setprio(0);
    __syncthreads();  // all waves done reading before next tile's DMA lands
  }

  // ---- merge the two s-halves per head ----
  float lt = l_part + __shfl_xor(l_part, 16, 64);
  lt = lt + __shfl_xor(lt, 32, 64);
  if (ln < 16) {
    msh[wv][ln] = m_run;
    lsh[wv][ln] = lt;
  }
  __syncthreads();  // publish (m,l); K/V reads all complete (loop-end barrier)
  const int pw_ = wv ^ 4;
  float mo = msh[pw_][r16], lpo = lsh[pw_][r16];
  float mf = fmaxf(m_run, mo);
  float fs = exp2f(m_run - mf);   // my scale
  float fo = exp2f(mo - mf);      // partner's scale
  float linv = 1.0f / fmaf(lt, fs, lpo * fo);
  float fj[4], ivj[4];
#pragma unroll
  for (int j = 0; j < 4; ++j) {
    fj[j] = __shfl(fs, (ln & 48) + g * 4 + j, 64);
    ivj[j] = __shfl(linv, (ln & 48) + g * 4 + j, 64);
  }
  float* Osc = (float*)smem + hw * 2048;  // [16][128] per head, overlays Ksh/Vsh
  if (sh == 0) {
#pragma unroll
    for (int db = 0; db < 8; ++db)
#pragma unroll
      for (int j = 0; j < 4; ++j)
        Osc[(g * 4 + j) * 128 + db * 16 + r16] = acc_o[db][j] * fj[j];
  }
  __syncthreads();  // publish scaled half-0
  if (sh == 1) {
#pragma unroll
    for (int j = 0; j < 4; ++j) {
      int tt = t0 + g * 4 + j;
      u16* orow = attn + (size_t)tt * HID + h * HD;
#pragma unroll
      for (int db = 0; db < 8; ++db) {
        float v = fmaf(acc_o[db][j], fj[j], Osc[(g * 4 + j) * 128 + db * 16 + r16]);
        orow[db * 16 + r16] = f2bf(v * ivj[j]);
      }
    }
  }
}

extern "C" void kernel_launch(void* const* d_in, const int* in_sizes, int n_in,
                              void* d_out, int out_size, void* d_ws, size_t ws_size,
                              hipStream_t stream) {
  const float* hs   = (const float*)d_in[0];
  const float* cs   = (const float*)d_in[1];
  const float* sn   = (const float*)d_in[2];
  const float* wqkv = (const float*)d_in[3];
  const float* qw   = (const float*)d_in[4];
  const float* kw   = (const float*)d_in[5];
  const float* wo   = (const float*)d_in[6];
  float* out = (float*)d_out;

  u16* ws      = (u16*)d_ws;
  u16* hs_bf   = ws;                       // 6291456 elems
  u16* wqkv_bf = hs_bf + 6291456;          // 6291456
  u16* wo_bf   = wqkv_bf + 6291456;        // 4194304
  u16* qkv     = wo_bf + 4194304;          // 9437184 (V region unused)
  u16* vt      = qkv + 9437184;            // 1572864  (V^T: [4*128][3072])
  u16* attn    = hs_bf;                    // reuse (hs_bf dead after GEMM1)

  k_cvt3<<<2560, 256, 0, stream>>>(hs, hs_bf, T_TOK * HID,
                                   wqkv, wqkv_bf, QKVN * HID,
                                   wo, wo_bf, HID * HID);
  // GEMM1: 3072x3072x2048, BM=BN=192 -> 16x16 = 256 blocks (1/CU, no tail)
  k_gemm2p<6, 3, true, true><<<dim3(16, 16), 512, 0, stream>>>(hs_bf, wqkv_bf, qkv, vt,
                                                               T_TOK, QKVN, HID);
  k_normrope<<<dim3(T_TOK, 5), 256, 0, stream>>>(qkv, cs, sn, qw, kw);
  k_attn<<<768, 512, 0, stream>>>(qkv, vt, attn);
  // GEMM2: 3072x2048x2048, BM=192 BN=128 -> 16x16 = 256 blocks
  k_gemm2p<6, 2, false, false><<<dim3(16, 16), 512, 0, stream>>>(attn, wo_bf, out, nullptr,
                                                                 T_TOK, HID, HID);
}

// Round 16
// 160.114 us; speedup vs baseline: 1.3556x; 1.3556x over previous
//
#include <hip/hip_runtime.h>

typedef unsigned short u16;
typedef unsigned int u32;
typedef __attribute__((ext_vector_type(8))) short bf16x8;
typedef __attribute__((ext_vector_type(4))) float f32x4;
typedef __attribute__((ext_vector_type(4))) u32 u32x4;

#define T_TOK 3072
#define HID 2048
#define NH 16
#define NKV 4
#define HD 128
#define QKVN 3072
#define ATT_SCALE 0.08838834764831845f
#define LOG2E 1.4426950408889634f
#define SCL2 (ATT_SCALE * LOG2E)

__device__ __forceinline__ u16 f2bf(float x) {
  u32 u = __builtin_bit_cast(u32, x);
  u = u + 0x7FFFu + ((u >> 16) & 1u);
  return (u16)(u >> 16);
}
__device__ __forceinline__ float bf2f(u16 h) {
  return __builtin_bit_cast(float, (u32)h << 16);
}
__device__ __forceinline__ u32 cvtpk(float lo, float hi) {
  u32 r;
  asm("v_cvt_pk_bf16_f32 %0, %1, %2" : "=v"(r) : "v"(lo), "v"(hi));
  return r;
}
__device__ __forceinline__ void gload16(const void* g, void* l) {
  __builtin_amdgcn_global_load_lds((const __attribute__((address_space(1))) void*)g,
                                   (__attribute__((address_space(3))) void*)l, 16, 0, 0);
}

// ---------------- fp32 -> bf16 convert, 3 regions in one launch ----------------
__global__ void k_cvt3(const float* __restrict__ s0p, u16* __restrict__ d0p, int n0,
                       const float* __restrict__ s1p, u16* __restrict__ d1p, int n1,
                       const float* __restrict__ s2p, u16* __restrict__ d2p, int n2) {
  const float* s;
  u16* d;
  int n, b = blockIdx.x, nb;
  if (b < 1024) {
    s = s0p; d = d0p; n = n0; nb = 1024;
  } else if (b < 2048) {
    s = s1p; d = d1p; n = n1; b -= 1024; nb = 1024;
  } else {
    s = s2p; d = d2p; n = n2; b -= 2048; nb = 512;
  }
  int i = (b * 256 + threadIdx.x) * 4;
  int stride = nb * 256 * 4;
  for (; i < n; i += stride) {
    float4 v = *(const float4*)(s + i);
    u32 lo = cvtpk(v.x, v.y);
    u32 hi = cvtpk(v.z, v.w);
    *(uint2*)(d + i) = make_uint2(lo, hi);
  }
}

// ---------------- 2-phase double-buffered GEMM: C = A * B^T ----------------
// (round-12 configuration — measured 42/28 µs)
template <int MR, int NR, bool OUT_BF16, bool VT_MODE>
__global__ __launch_bounds__(512) void k_gemm2p(const u16* __restrict__ A,
                                                const u16* __restrict__ B,
                                                void* __restrict__ Cp,
                                                u16* __restrict__ vt,
                                                int M, int N, int K) {
  constexpr int BM = 32 * MR;
  constexpr int BN = 64 * NR;
  __shared__ u16 Ash[2][BM * 64];
  __shared__ u16 Bsh[2][BN * 64];
  const int tid = threadIdx.x;
  const int wv = tid >> 6, ln = tid & 63;
  const int wr = wv >> 2, wc = wv & 3;
  const int g = ln >> 4, r16 = ln & 15;
  const int m0 = blockIdx.y * BM, n0 = blockIdx.x * BN;
  const int NT = K >> 6;
  const int srow = ln >> 3;                   // row within 8-row DMA block
  const int sswz = ((ln & 7) ^ srow) << 3;    // pre-swizzled source col (elems)
  const u16* Abase = A + (size_t)m0 * K;
  const u16* Bbase = B + (size_t)n0 * K;
  const int xorc = (r16 & 7) << 3;

  f32x4 acc[MR][NR] = {};

  auto stage = [&](int buf, int T) {
#pragma unroll
    for (int a = 0; a < BM / 64; ++a)
      gload16(Abase + (size_t)(a * 64 + wv * 8 + srow) * K + T * 64 + sswz,
              &Ash[buf][(a * 64 + wv * 8) * 64]);
#pragma unroll
    for (int b = 0; b < BN / 64; ++b)
      gload16(Bbase + (size_t)(b * 64 + wv * 8 + srow) * K + T * 64 + sswz,
              &Bsh[buf][(b * 64 + wv * 8) * 64]);
  };

  stage(0, 0);
  __syncthreads();
  int cur = 0;
  for (int T = 0; T < NT; ++T) {
    if (T + 1 < NT) stage(cur ^ 1, T + 1);
    const u16* As = Ash[cur];
    const u16* Bs = Bsh[cur];
#pragma unroll
    for (int kk = 0; kk < 2; ++kk) {
      const int ecol = (kk * 32 + g * 8) ^ xorc;
      bf16x8 af[MR], bfr[NR];
#pragma unroll
      for (int m = 0; m < MR; ++m)
        af[m] = *(const bf16x8*)&As[(wr * (MR * 16) + m * 16 + r16) * 64 + ecol];
#pragma unroll
      for (int n = 0; n < NR; ++n)
        bfr[n] = *(const bf16x8*)&Bs[(wc * (NR * 16) + n * 16 + r16) * 64 + ecol];
      __builtin_amdgcn_s_setprio(1);
#pragma unroll
      for (int m = 0; m < MR; ++m)
#pragma unroll
        for (int n = 0; n < NR; ++n)
          acc[m][n] = __builtin_amdgcn_mfma_f32_16x16x32_bf16(af[m], bfr[n], acc[m][n], 0, 0, 0);
      __builtin_amdgcn_s_setprio(0);
    }
    __syncthreads();
    cur ^= 1;
  }
  // ---- epilogue ----
#pragma unroll
  for (int n = 0; n < NR; ++n) {
    int col = n0 + wc * (NR * 16) + n * 16 + r16;
    bool tov = VT_MODE && (col >= 2560);
#pragma unroll
    for (int m = 0; m < MR; ++m) {
      int row = m0 + wr * (MR * 16) + m * 16 + g * 4;
      if (tov) {
        u32 lo2 = (u32)f2bf(acc[m][n][0]) | ((u32)f2bf(acc[m][n][1]) << 16);
        u32 hi2 = (u32)f2bf(acc[m][n][2]) | ((u32)f2bf(acc[m][n][3]) << 16);
        *(uint2*)&vt[(size_t)(col - 2560) * T_TOK + row] = make_uint2(lo2, hi2);
      } else {
#pragma unroll
        for (int j = 0; j < 4; ++j) {
          if (OUT_BF16)
            ((u16*)Cp)[(size_t)(row + j) * N + col] = f2bf(acc[m][n][j]);
          else
            ((float*)Cp)[(size_t)(row + j) * N + col] = acc[m][n][j];
        }
      }
    }
  }
}

// ---------------- RMSNorm + RoPE (in-place on bf16 qkv, Q and K only) ----------------
__global__ void k_normrope(u16* __restrict__ qkv, const float* __restrict__ cs,
                           const float* __restrict__ sn, const float* __restrict__ qw,
                           const float* __restrict__ kw) {
  int t = blockIdx.x;
  int idx = blockIdx.y * 4 + (threadIdx.x >> 6);  // 0..19
  int l = threadIdx.x & 63;
  bool isq = idx < NH;
  int off = isq ? idx * HD : HID + (idx - NH) * HD;
  u16* p = qkv + (size_t)t * QKVN + off;
  float x0 = bf2f(p[l]), x1 = bf2f(p[l + 64]);
  float ss = x0 * x0 + x1 * x1;
#pragma unroll
  for (int d = 1; d < 64; d <<= 1) ss += __shfl_xor(ss, d, 64);
  float rs = rsqrtf(ss * (1.0f / 128.0f) + 1e-6f);
  const float* w = isq ? qw : kw;
  float xn0 = x0 * rs * w[l];
  float xn1 = x1 * rs * w[l + 64];
  const float* ct = cs + (size_t)t * HD;
  const float* st = sn + (size_t)t * HD;
  float o0 = xn0 * ct[l] - xn1 * st[l];
  float o1 = xn1 * ct[l + 64] + xn0 * st[l + 64];
  p[l] = f2bf(o0);
  p[l + 64] = f2bf(o1);
}

// ---------------- GQA attention, split-s across blocks ----------------
// Round-12 kernel (proven: 64 VGPR, 32KB LDS, no spill) with the s-range of
// each (t0, head) q-group split across TWO blocks (sp=0: first nt/2 tiles,
// sp=1: rest). Each writes unnormalized partial O (bf16) + per-row (m,l);
// k_mergeattn combines. Grid 1536 -> ~5 resident blocks/CU (was ~3).
__global__ __launch_bounds__(256, 4) void k_attn_sp(const u16* __restrict__ qkv,
                                                    const u16* __restrict__ vt,
                                                    u16* __restrict__ O0,
                                                    u16* __restrict__ O1,
                                                    float* __restrict__ ml) {
  __shared__ u16 Ksh[64 * 128];     // [s][granule ^ (s&7)]
  __shared__ u16 Vsh[128 * 64];     // [d][granule ^ (d&7)]
  const int id = blockIdx.x;
  const int xcd = id & 7, slot = id >> 3;              // slot 0..191
  const int sp = slot & 1;                             // s-range split index
  const int qslot = slot >> 1;                         // 0..95
  const int hkv = xcd >> 1;                            // 2 XCDs per kv-group
  const int t0 = (191 - (qslot * 2 + (xcd & 1))) * 16; // reversed: long blocks first
  const int tid = threadIdx.x, wv = tid >> 6, ln = tid & 63;
  const int g = ln >> 4, r16 = ln & 15;
  const int h = hkv * 4 + wv;
  const int swz = r16 & 7;
  const bool ghi = (g >> 1) != 0;
  const int L0 = r16 + 16 * ((2 * g) & 3);   // src lanes for P-fragment shfl
  const int L1 = r16 + 16 * ((2 * g + 1) & 3);

  bf16x8 qf[4];
  const u16* qrow = qkv + (size_t)(t0 + r16) * QKVN + h * HD;
#pragma unroll
  for (int kk = 0; kk < 4; ++kk) qf[kk] = *(const bf16x8*)(qrow + kk * 32 + g * 8);

  float m_run = -1e30f, l_part = 0.f;   // row t = t0 + r16 (per-lane)
  f32x4 acc_o[8] = {};                  // rows t = t0 + g*4+j, cols d = db*16+r16

  const u16* Kbase = qkv + HID + hkv * HD;
  const u16* Vbase = vt + (size_t)(hkv * HD) * T_TOK;

  int lo = t0 - 1023;
  if (lo < 0) lo = 0;
  lo &= ~63;
  const int t_hi = t0 + 15;
  const int nt = ((t_hi - lo) >> 6) + 1;
  const int nth = nt >> 1;
  const int tbeg = sp ? nth : 0;
  const int tend = sp ? nt : nth;

  for (int ti = tbeg; ti < tend; ++ti) {
    const int s0 = lo + ti * 64;
    // ---- stage K [64][128] + V^T [128][64] via global_load_lds ----
#pragma unroll
    for (int ph = 0; ph < 4; ++ph) {
      int ks = wv * 16 + ph * 4 + (ln >> 4);
      int kc = (ln & 15) ^ (ks & 7);
      gload16(Kbase + (size_t)(s0 + ks) * QKVN + (kc << 3),
              &Ksh[(wv * 16 + ph * 4) * 128]);
      int vd = wv * 32 + ph * 8 + (ln >> 3);
      int vc = (ln & 7) ^ (vd & 7);
      gload16(Vbase + (size_t)vd * T_TOK + s0 + (vc << 3),
              &Vsh[(wv * 32 + ph * 8) * 64]);
    }
    __syncthreads();  // drains vmcnt(0): staged data visible

    // ---- S^T = K Q^T (swapped): sc[sb] rows s_local=g*4+j, cols t=r16 ----
    f32x4 sc[4] = {};
    __builtin_amdgcn_s_setprio(1);
#pragma unroll
    for (int sb = 0; sb < 4; ++sb) {
#pragma unroll
      for (int kk = 0; kk < 4; ++kk) {
        const bf16x8 kf =
            *(const bf16x8*)&Ksh[(sb * 16 + r16) * 128 + (((kk * 4 + g) ^ swz) << 3)];
        sc[sb] = __builtin_amdgcn_mfma_f32_16x16x32_bf16(kf, qf[kk], sc[sb], 0, 0, 0);
      }
    }
    __builtin_amdgcn_s_setprio(0);

    // ---- mask (specialized: only last tile + window tile) + row max ----
    const bool mtile = (s0 > t0 - 60) || (t0 >= 1024 && s0 == lo);
    const int t = t0 + r16;
    float pmax = -__builtin_inff();
    if (mtile) {
#pragma unroll
      for (int sb = 0; sb < 4; ++sb)
#pragma unroll
        for (int j = 0; j < 4; ++j) {
          int s = s0 + sb * 16 + g * 4 + j;
          bool ok = (s <= (t | 3)) && (t - s < 1024);
          float x = ok ? sc[sb][j] : -__builtin_inff();
          sc[sb][j] = x;
          pmax = fmaxf(pmax, x);
        }
    } else {
#pragma unroll
      for (int sb = 0; sb < 4; ++sb)
#pragma unroll
        for (int j = 0; j < 4; ++j) pmax = fmaxf(pmax, sc[sb][j]);
    }
    pmax = fmaxf(pmax, __shfl_xor(pmax, 16, 64));
    pmax = fmaxf(pmax, __shfl_xor(pmax, 32, 64));

    // ---- defer-max online softmax (log2 domain) ----
    float needv = fmaf(pmax, SCL2, -m_run);
    if (!__all(needv <= 11.5f)) {
      float mnew = fmaxf(m_run, pmax * SCL2);
      float fac = exp2f(m_run - mnew);
      m_run = mnew;
      l_part *= fac;
      float fj[4];
#pragma unroll
      for (int j = 0; j < 4; ++j) fj[j] = __shfl(fac, (ln & 48) + g * 4 + j, 64);
#pragma unroll
      for (int db = 0; db < 8; ++db)
#pragma unroll
        for (int j = 0; j < 4; ++j) acc_o[db][j] *= fj[j];
    }
    const float nm = -m_run;
    u32 w0[4], w1[4];
#pragma unroll
    for (int sb = 0; sb < 4; ++sb) {
      float e0 = exp2f(fmaf(sc[sb][0], SCL2, nm));
      float e1 = exp2f(fmaf(sc[sb][1], SCL2, nm));
      float e2 = exp2f(fmaf(sc[sb][2], SCL2, nm));
      float e3 = exp2f(fmaf(sc[sb][3], SCL2, nm));
      l_part += (e0 + e1) + (e2 + e3);
      w0[sb] = cvtpk(e0, e1);
      w1[sb] = cvtpk(e2, e3);
    }

    // ---- O += P V: P rearranged lane->A-fragment via shfl (no LDS) ----
    __builtin_amdgcn_s_setprio(1);
#pragma unroll
    for (int s32 = 0; s32 < 2; ++s32) {
      u32 a0 = __shfl(w0[2 * s32], L0, 64), b0 = __shfl(w0[2 * s32 + 1], L0, 64);
      u32 a1 = __shfl(w1[2 * s32], L0, 64), b1 = __shfl(w1[2 * s32 + 1], L0, 64);
      u32 a2 = __shfl(w0[2 * s32], L1, 64), b2 = __shfl(w0[2 * s32 + 1], L1, 64);
      u32 a3 = __shfl(w1[2 * s32], L1, 64), b3 = __shfl(w1[2 * s32 + 1], L1, 64);
      u32x4 pw;
      pw[0] = ghi ? b0 : a0;
      pw[1] = ghi ? b1 : a1;
      pw[2] = ghi ? b2 : a2;
      pw[3] = ghi ? b3 : a3;
      const bf16x8 pa = __builtin_bit_cast(bf16x8, pw);
#pragma unroll
      for (int db = 0; db < 8; ++db) {
        const bf16x8 vb =
            *(const bf16x8*)&Vsh[(db * 16 + r16) * 64 + (((s32 * 4 + g) ^ swz) << 3)];
        acc_o[db] = __builtin_amdgcn_mfma_f32_16x16x32_bf16(pa, vb, acc_o[db], 0, 0, 0);
      }
    }
    __builtin_amdgcn_s_setprio(0);
    __syncthreads();  // all waves done reading before next tile's DMA lands
  }

  // ---- epilogue: publish (m, l) and unnormalized partial O ----
  float lt = l_part + __shfl_xor(l_part, 16, 64);
  lt = lt + __shfl_xor(lt, 32, 64);
  if (ln < 16) {
    float* mlp = ml + ((size_t)(sp * T_TOK) + t0 + ln) * (2 * NH) + h * 2;
    mlp[0] = m_run;
    mlp[1] = lt;
  }
  u16* Op = sp ? O1 : O0;
#pragma unroll
  for (int j = 0; j < 4; ++j) {
    int tt = t0 + g * 4 + j;
    u16* orow = Op + (size_t)tt * HID + h * HD;
#pragma unroll
    for (int db = 0; db < 8; ++db) orow[db * 16 + r16] = f2bf(acc_o[db][j]);
  }
}

// ---------------- merge the two s-split partials ----------------
// out[t][c] = (O0*fs0 + O1*fs1) / (l0*fs0 + l1*fs1), fs_i = exp2(m_i - max).
// In-place on O0 (= the attn buffer GEMM2 reads). 16 elems/thread.
__global__ void k_mergeattn(u16* __restrict__ O0, const u16* __restrict__ O1,
                            const float* __restrict__ ml) {
  int f0 = (blockIdx.x * 256 + threadIdx.x) * 16;
  int t = f0 >> 11;
  int h = (f0 >> 7) & 15;
  const float* p0 = ml + (size_t)t * (2 * NH) + h * 2;
  const float* p1 = ml + ((size_t)T_TOK + t) * (2 * NH) + h * 2;
  float m0 = p0[0], l0 = p0[1], m1 = p1[0], l1 = p1[1];
  float mf = fmaxf(m0, m1);
  float fs0 = exp2f(m0 - mf), fs1 = exp2f(m1 - mf);
  float linv = 1.0f / fmaf(l0, fs0, l1 * fs1);
  fs0 *= linv;
  fs1 *= linv;
#pragma unroll
  for (int k = 0; k < 16; k += 8) {
    u32x4 a = *(const u32x4*)(O0 + f0 + k);
    u32x4 b = *(const u32x4*)(O1 + f0 + k);
    u32x4 r;
#pragma unroll
    for (int q = 0; q < 4; ++q) {
      float alo = bf2f((u16)(a[q] & 0xffff)), ahi = bf2f((u16)(a[q] >> 16));
      float blo = bf2f((u16)(b[q] & 0xffff)), bhi = bf2f((u16)(b[q] >> 16));
      float vlo = fmaf(alo, fs0, blo * fs1);
      float vhi = fmaf(ahi, fs0, bhi * fs1);
      r[q] = cvtpk(vlo, vhi);
    }
    *(u32x4*)(O0 + f0 + k) = r;
  }
}

extern "C" void kernel_launch(void* const* d_in, const int* in_sizes, int n_in,
                              void* d_out, int out_size, void* d_ws, size_t ws_size,
                              hipStream_t stream) {
  const float* hs   = (const float*)d_in[0];
  const float* cs   = (const float*)d_in[1];
  const float* sn   = (const float*)d_in[2];
  const float* wqkv = (const float*)d_in[3];
  const float* qw   = (const float*)d_in[4];
  const float* kw   = (const float*)d_in[5];
  const float* wo   = (const float*)d_in[6];
  float* out = (float*)d_out;

  u16* ws      = (u16*)d_ws;
  u16* hs_bf   = ws;                       // 6291456 elems
  u16* wqkv_bf = hs_bf + 6291456;          // 6291456 (dead after GEMM1 -> O1)
  u16* wo_bf   = wqkv_bf + 6291456;        // 4194304
  u16* qkv     = wo_bf + 4194304;          // 9437184 (V region unused)
  u16* vt      = qkv + 9437184;            // 1572864  (V^T: [4*128][3072])
  float* mlbuf = (float*)(vt + 1572864);   // 196608 floats (m,l partials)
  u16* attn    = hs_bf;                    // O0 / merged attn (dead after GEMM1)

  k_cvt3<<<2560, 256, 0, stream>>>(hs, hs_bf, T_TOK * HID,
                                   wqkv, wqkv_bf, QKVN * HID,
                                   wo, wo_bf, HID * HID);
  // GEMM1: 3072x3072x2048, BM=BN=192 -> 16x16 = 256 blocks (1/CU, no tail)
  k_gemm2p<6, 3, true, true><<<dim3(16, 16), 512, 0, stream>>>(hs_bf, wqkv_bf, qkv, vt,
                                                               T_TOK, QKVN, HID);
  k_normrope<<<dim3(T_TOK, 5), 256, 0, stream>>>(qkv, cs, sn, qw, kw);
  k_attn_sp<<<1536, 256, 0, stream>>>(qkv, vt, attn, wqkv_bf, mlbuf);
  k_mergeattn<<<1536, 256, 0, stream>>>(attn, wqkv_bf, mlbuf);
  // GEMM2: 3072x2048x2048, BM=192 BN=128 -> 16x16 = 256 blocks
  k_gemm2p<6, 2, false, false><<<dim3(16, 16), 512, 0, stream>>>(attn, wo_bf, out, nullptr,
                                                                 T_TOK, HID, HID);
}

// Round 17
// 151.079 us; speedup vs baseline: 1.4366x; 1.0598x over previous
//
#include <hip/hip_runtime.h>

typedef unsigned short u16;
typedef unsigned int u32;
typedef __attribute__((ext_vector_type(8))) short bf16x8;
typedef __attribute__((ext_vector_type(4))) float f32x4;
typedef __attribute__((ext_vector_type(4))) u32 u32x4;

#define T_TOK 3072
#define HID 2048
#define NH 16
#define NKV 4
#define HD 128
#define QKVN 3072
#define ATT_SCALE 0.08838834764831845f
#define LOG2E 1.4426950408889634f
#define SCL2 (ATT_SCALE * LOG2E)

__device__ __forceinline__ u16 f2bf(float x) {
  u32 u = __builtin_bit_cast(u32, x);
  u = u + 0x7FFFu + ((u >> 16) & 1u);
  return (u16)(u >> 16);
}
__device__ __forceinline__ float bf2f(u16 h) {
  return __builtin_bit_cast(float, (u32)h << 16);
}
__device__ __forceinline__ u32 cvtpk(float lo, float hi) {
  u32 r;
  asm("v_cvt_pk_bf16_f32 %0, %1, %2" : "=v"(r) : "v"(lo), "v"(hi));
  return r;
}
__device__ __forceinline__ void gload16(const void* g, void* l) {
  __builtin_amdgcn_global_load_lds((const __attribute__((address_space(1))) void*)g,
                                   (__attribute__((address_space(3))) void*)l, 16, 0, 0);
}

// ---------------- fp32 -> bf16 convert, 3 regions in one launch ----------------
__global__ void k_cvt3(const float* __restrict__ s0p, u16* __restrict__ d0p, int n0,
                       const float* __restrict__ s1p, u16* __restrict__ d1p, int n1,
                       const float* __restrict__ s2p, u16* __restrict__ d2p, int n2) {
  const float* s;
  u16* d;
  int n, b = blockIdx.x, nb;
  if (b < 1024) {
    s = s0p; d = d0p; n = n0; nb = 1024;
  } else if (b < 2048) {
    s = s1p; d = d1p; n = n1; b -= 1024; nb = 1024;
  } else {
    s = s2p; d = d2p; n = n2; b -= 2048; nb = 512;
  }
  int i = (b * 256 + threadIdx.x) * 4;
  int stride = nb * 256 * 4;
  for (; i < n; i += stride) {
    float4 v = *(const float4*)(s + i);
    u32 lo = cvtpk(v.x, v.y);
    u32 hi = cvtpk(v.z, v.w);
    *(uint2*)(d + i) = make_uint2(lo, hi);
  }
}

// ---------------- 2-phase double-buffered GEMM: C = A * B^T ----------------
// (round-12 configuration — measured 42/28 µs)
template <int MR, int NR, bool OUT_BF16, bool VT_MODE>
__global__ __launch_bounds__(512) void k_gemm2p(const u16* __restrict__ A,
                                                const u16* __restrict__ B,
                                                void* __restrict__ Cp,
                                                u16* __restrict__ vt,
                                                int M, int N, int K) {
  constexpr int BM = 32 * MR;
  constexpr int BN = 64 * NR;
  __shared__ u16 Ash[2][BM * 64];
  __shared__ u16 Bsh[2][BN * 64];
  const int tid = threadIdx.x;
  const int wv = tid >> 6, ln = tid & 63;
  const int wr = wv >> 2, wc = wv & 3;
  const int g = ln >> 4, r16 = ln & 15;
  const int m0 = blockIdx.y * BM, n0 = blockIdx.x * BN;
  const int NT = K >> 6;
  const int srow = ln >> 3;                   // row within 8-row DMA block
  const int sswz = ((ln & 7) ^ srow) << 3;    // pre-swizzled source col (elems)
  const u16* Abase = A + (size_t)m0 * K;
  const u16* Bbase = B + (size_t)n0 * K;
  const int xorc = (r16 & 7) << 3;

  f32x4 acc[MR][NR] = {};

  auto stage = [&](int buf, int T) {
#pragma unroll
    for (int a = 0; a < BM / 64; ++a)
      gload16(Abase + (size_t)(a * 64 + wv * 8 + srow) * K + T * 64 + sswz,
              &Ash[buf][(a * 64 + wv * 8) * 64]);
#pragma unroll
    for (int b = 0; b < BN / 64; ++b)
      gload16(Bbase + (size_t)(b * 64 + wv * 8 + srow) * K + T * 64 + sswz,
              &Bsh[buf][(b * 64 + wv * 8) * 64]);
  };

  stage(0, 0);
  __syncthreads();
  int cur = 0;
  for (int T = 0; T < NT; ++T) {
    if (T + 1 < NT) stage(cur ^ 1, T + 1);
    const u16* As = Ash[cur];
    const u16* Bs = Bsh[cur];
#pragma unroll
    for (int kk = 0; kk < 2; ++kk) {
      const int ecol = (kk * 32 + g * 8) ^ xorc;
      bf16x8 af[MR], bfr[NR];
#pragma unroll
      for (int m = 0; m < MR; ++m)
        af[m] = *(const bf16x8*)&As[(wr * (MR * 16) + m * 16 + r16) * 64 + ecol];
#pragma unroll
      for (int n = 0; n < NR; ++n)
        bfr[n] = *(const bf16x8*)&Bs[(wc * (NR * 16) + n * 16 + r16) * 64 + ecol];
      __builtin_amdgcn_s_setprio(1);
#pragma unroll
      for (int m = 0; m < MR; ++m)
#pragma unroll
        for (int n = 0; n < NR; ++n)
          acc[m][n] = __builtin_amdgcn_mfma_f32_16x16x32_bf16(af[m], bfr[n], acc[m][n], 0, 0, 0);
      __builtin_amdgcn_s_setprio(0);
    }
    __syncthreads();
    cur ^= 1;
  }
  // ---- epilogue ----
#pragma unroll
  for (int n = 0; n < NR; ++n) {
    int col = n0 + wc * (NR * 16) + n * 16 + r16;
    bool tov = VT_MODE && (col >= 2560);
#pragma unroll
    for (int m = 0; m < MR; ++m) {
      int row = m0 + wr * (MR * 16) + m * 16 + g * 4;
      if (tov) {
        u32 lo2 = (u32)f2bf(acc[m][n][0]) | ((u32)f2bf(acc[m][n][1]) << 16);
        u32 hi2 = (u32)f2bf(acc[m][n][2]) | ((u32)f2bf(acc[m][n][3]) << 16);
        *(uint2*)&vt[(size_t)(col - 2560) * T_TOK + row] = make_uint2(lo2, hi2);
      } else {
#pragma unroll
        for (int j = 0; j < 4; ++j) {
          if (OUT_BF16)
            ((u16*)Cp)[(size_t)(row + j) * N + col] = f2bf(acc[m][n][j]);
          else
            ((float*)Cp)[(size_t)(row + j) * N + col] = acc[m][n][j];
        }
      }
    }
  }
}

// ---------------- RMSNorm + RoPE for K heads only (Q fused into attn) ----------------
__global__ void k_normropeK(u16* __restrict__ qkv, const float* __restrict__ cs,
                            const float* __restrict__ sn, const float* __restrict__ kw) {
  int t = blockIdx.x;
  int kh = threadIdx.x >> 6;      // 0..3
  int l = threadIdx.x & 63;
  u16* p = qkv + (size_t)t * QKVN + HID + kh * HD;
  float x0 = bf2f(p[l]), x1 = bf2f(p[l + 64]);
  float ss = x0 * x0 + x1 * x1;
#pragma unroll
  for (int d = 1; d < 64; d <<= 1) ss += __shfl_xor(ss, d, 64);
  float rs = rsqrtf(ss * (1.0f / 128.0f) + 1e-6f);
  float xn0 = x0 * rs * kw[l];
  float xn1 = x1 * rs * kw[l + 64];
  const float* ct = cs + (size_t)t * HD;
  const float* st = sn + (size_t)t * HD;
  float o0 = xn0 * ct[l] - xn1 * st[l];
  float o1 = xn1 * ct[l + 64] + xn0 * st[l + 64];
  p[l] = f2bf(o0);
  p[l + 64] = f2bf(o1);
}

// ---------------- GQA attention: swapped-QK in-reg softmax, DMA-staged LDS ----------------
// Round-12 kernel (57.4 µs proven) + fused Q RMSNorm/RoPE at Q-load (one-time,
// pre-loop; transients dead before the flash loop's live set peaks).
__global__ __launch_bounds__(256, 4) void k_attn(const u16* __restrict__ qkv,
                                                 const u16* __restrict__ vt,
                                                 const float* __restrict__ cs,
                                                 const float* __restrict__ sn,
                                                 const float* __restrict__ qw,
                                                 u16* __restrict__ attn) {
  __shared__ u16 Ksh[64 * 128];     // [s][granule ^ (s&7)]
  __shared__ u16 Vsh[128 * 64];     // [d][granule ^ (d&7)]
  const int id = blockIdx.x;
  const int xcd = id & 7, slot = id >> 3;              // slot 0..95
  const int hkv = xcd >> 1;                            // 2 XCDs per kv-group
  const int t0 = (191 - (slot * 2 + (xcd & 1))) * 16;  // reversed: long blocks first
  const int tid = threadIdx.x, wv = tid >> 6, ln = tid & 63;
  const int g = ln >> 4, r16 = ln & 15;
  const int h = hkv * 4 + wv;
  const int swz = r16 & 7;
  const bool ghi = (g >> 1) != 0;
  const int L0 = r16 + 16 * ((2 * g) & 3);   // src lanes for P-fragment shfl
  const int L1 = r16 + 16 * ((2 * g + 1) & 3);

  // ---- one-time: load raw Q, RMSNorm + RoPE in fp32, pack to bf16 fragments ----
  bf16x8 qf[4];
  {
    const u16* qrow = qkv + (size_t)(t0 + r16) * QKVN + h * HD;
    float xn[4][8];
    float ss = 0.f;
#pragma unroll
    for (int kk = 0; kk < 4; ++kk) {
      bf16x8 v = *(const bf16x8*)(qrow + kk * 32 + g * 8);
#pragma unroll
      for (int e = 0; e < 8; ++e) {
        float x = bf2f((u16)v[e]);
        xn[kk][e] = x;
        ss = fmaf(x, x, ss);
      }
    }
    ss += __shfl_xor(ss, 16, 64);
    ss += __shfl_xor(ss, 32, 64);
    float rs = rsqrtf(ss * (1.0f / 128.0f) + 1e-6f);
#pragma unroll
    for (int kk = 0; kk < 4; ++kk) {
      const int d0 = kk * 32 + g * 8;
      float4 w0v = *(const float4*)(qw + d0);
      float4 w1v = *(const float4*)(qw + d0 + 4);
#pragma unroll
      for (int e = 0; e < 4; ++e) xn[kk][e] *= rs * (&w0v.x)[e];
#pragma unroll
      for (int e = 0; e < 4; ++e) xn[kk][4 + e] *= rs * (&w1v.x)[e];
    }
    const float* ct = cs + (size_t)(t0 + r16) * HD;
    const float* st = sn + (size_t)(t0 + r16) * HD;
#pragma unroll
    for (int kk = 0; kk < 4; ++kk) {
      const int d0 = kk * 32 + g * 8;
      float4 c0 = *(const float4*)(ct + d0);
      float4 c1 = *(const float4*)(ct + d0 + 4);
      float4 s0v = *(const float4*)(st + d0);
      float4 s1v = *(const float4*)(st + d0 + 4);
      float o[8];
#pragma unroll
      for (int e = 0; e < 8; ++e) {
        float cc = e < 4 ? (&c0.x)[e] : (&c1.x)[e - 4];
        float sv = e < 4 ? (&s0v.x)[e] : (&s1v.x)[e - 4];
        float a = xn[kk][e];
        float b = (kk < 2) ? xn[kk + 2][e] : xn[kk - 2][e];
        o[e] = (kk < 2) ? (a * cc - b * sv) : fmaf(a, cc, b * sv);
      }
      u32x4 pk;
#pragma unroll
      for (int q = 0; q < 4; ++q) pk[q] = cvtpk(o[2 * q], o[2 * q + 1]);
      qf[kk] = __builtin_bit_cast(bf16x8, pk);
    }
  }

  float m_run = -1e30f, l_part = 0.f;   // row t = t0 + r16 (per-lane)
  f32x4 acc_o[8] = {};                  // rows t = t0 + g*4+j, cols d = db*16+r16

  const u16* Kbase = qkv + HID + hkv * HD;
  const u16* Vbase = vt + (size_t)(hkv * HD) * T_TOK;

  int lo = t0 - 1023;
  if (lo < 0) lo = 0;
  lo &= ~63;
  const int t_hi = t0 + 15;

  for (int s0 = lo; s0 <= t_hi; s0 += 64) {
    // ---- stage K [64][128] + V^T [128][64] via global_load_lds ----
#pragma unroll
    for (int ph = 0; ph < 4; ++ph) {
      int ks = wv * 16 + ph * 4 + (ln >> 4);
      int kc = (ln & 15) ^ (ks & 7);
      gload16(Kbase + (size_t)(s0 + ks) * QKVN + (kc << 3),
              &Ksh[(wv * 16 + ph * 4) * 128]);
      int vd = wv * 32 + ph * 8 + (ln >> 3);
      int vc = (ln & 7) ^ (vd & 7);
      gload16(Vbase + (size_t)vd * T_TOK + s0 + (vc << 3),
              &Vsh[(wv * 32 + ph * 8) * 64]);
    }
    __syncthreads();  // drains vmcnt(0): staged data visible

    // ---- S^T = K Q^T (swapped): sc[sb] rows s_local=g*4+j, cols t=r16 ----
    f32x4 sc[4] = {};
    __builtin_amdgcn_s_setprio(1);
#pragma unroll
    for (int sb = 0; sb < 4; ++sb) {
#pragma unroll
      for (int kk = 0; kk < 4; ++kk) {
        const bf16x8 kf =
            *(const bf16x8*)&Ksh[(sb * 16 + r16) * 128 + (((kk * 4 + g) ^ swz) << 3)];
        sc[sb] = __builtin_amdgcn_mfma_f32_16x16x32_bf16(kf, qf[kk], sc[sb], 0, 0, 0);
      }
    }
    __builtin_amdgcn_s_setprio(0);

    // ---- mask (specialized: only last tile + window tile) + row max ----
    const bool mtile = (s0 > t0 - 60) || (t0 >= 1024 && s0 == lo);
    const int t = t0 + r16;
    float pmax = -__builtin_inff();
    if (mtile) {
#pragma unroll
      for (int sb = 0; sb < 4; ++sb)
#pragma unroll
        for (int j = 0; j < 4; ++j) {
          int s = s0 + sb * 16 + g * 4 + j;
          bool ok = (s <= (t | 3)) && (t - s < 1024);
          float x = ok ? sc[sb][j] : -__builtin_inff();
          sc[sb][j] = x;
          pmax = fmaxf(pmax, x);
        }
    } else {
#pragma unroll
      for (int sb = 0; sb < 4; ++sb)
#pragma unroll
        for (int j = 0; j < 4; ++j) pmax = fmaxf(pmax, sc[sb][j]);
    }
    pmax = fmaxf(pmax, __shfl_xor(pmax, 16, 64));
    pmax = fmaxf(pmax, __shfl_xor(pmax, 32, 64));

    // ---- defer-max online softmax (log2 domain) ----
    float needv = fmaf(pmax, SCL2, -m_run);
    if (!__all(needv <= 11.5f)) {
      float mnew = fmaxf(m_run, pmax * SCL2);
      float fac = exp2f(m_run - mnew);
      m_run = mnew;
      l_part *= fac;
      float fj[4];
#pragma unroll
      for (int j = 0; j < 4; ++j) fj[j] = __shfl(fac, (ln & 48) + g * 4 + j, 64);
#pragma unroll
      for (int db = 0; db < 8; ++db)
#pragma unroll
        for (int j = 0; j < 4; ++j) acc_o[db][j] *= fj[j];
    }
    const float nm = -m_run;
    u32 w0[4], w1[4];
#pragma unroll
    for (int sb = 0; sb < 4; ++sb) {
      float e0 = exp2f(fmaf(sc[sb][0], SCL2, nm));
      float e1 = exp2f(fmaf(sc[sb][1], SCL2, nm));
      float e2 = exp2f(fmaf(sc[sb][2], SCL2, nm));
      float e3 = exp2f(fmaf(sc[sb][3], SCL2, nm));
      l_part += (e0 + e1) + (e2 + e3);
      w0[sb] = cvtpk(e0, e1);
      w1[sb] = cvtpk(e2, e3);
    }

    // ---- O += P V: P rearranged lane->A-fragment via shfl (no LDS) ----
    __builtin_amdgcn_s_setprio(1);
#pragma unroll
    for (int s32 = 0; s32 < 2; ++s32) {
      u32 a0 = __shfl(w0[2 * s32], L0, 64), b0 = __shfl(w0[2 * s32 + 1], L0, 64);
      u32 a1 = __shfl(w1[2 * s32], L0, 64), b1 = __shfl(w1[2 * s32 + 1], L0, 64);
      u32 a2 = __shfl(w0[2 * s32], L1, 64), b2 = __shfl(w0[2 * s32 + 1], L1, 64);
      u32 a3 = __shfl(w1[2 * s32], L1, 64), b3 = __shfl(w1[2 * s32 + 1], L1, 64);
      u32x4 pw;
      pw[0] = ghi ? b0 : a0;
      pw[1] = ghi ? b1 : a1;
      pw[2] = ghi ? b2 : a2;
      pw[3] = ghi ? b3 : a3;
      const bf16x8 pa = __builtin_bit_cast(bf16x8, pw);
#pragma unroll
      for (int db = 0; db < 8; ++db) {
        const bf16x8 vb =
            *(const bf16x8*)&Vsh[(db * 16 + r16) * 64 + (((s32 * 4 + g) ^ swz) << 3)];
        acc_o[db] = __builtin_amdgcn_mfma_f32_16x16x32_bf16(pa, vb, acc_o[db], 0, 0, 0);
      }
    }
    __builtin_amdgcn_s_setprio(0);
    __syncthreads();  // all waves done reading before next tile's DMA lands
  }

  // ---- epilogue: finalize l (cross-group), broadcast to acc layout ----
  float lt = l_part + __shfl_xor(l_part, 16, 64);
  lt = lt + __shfl_xor(lt, 32, 64);
  float inv = 1.0f / lt;
  float ij[4];
#pragma unroll
  for (int j = 0; j < 4; ++j) ij[j] = __shfl(inv, (ln & 48) + g * 4 + j, 64);
#pragma unroll
  for (int j = 0; j < 4; ++j) {
    int tt = t0 + g * 4 + j;
    u16* orow = attn + (size_t)tt * HID + h * HD;
#pragma unroll
    for (int db = 0; db < 8; ++db) orow[db * 16 + r16] = f2bf(acc_o[db][j] * ij[j]);
  }
}

extern "C" void kernel_launch(void* const* d_in, const int* in_sizes, int n_in,
                              void* d_out, int out_size, void* d_ws, size_t ws_size,
                              hipStream_t stream) {
  const float* hs   = (const float*)d_in[0];
  const float* cs   = (const float*)d_in[1];
  const float* sn   = (const float*)d_in[2];
  const float* wqkv = (const float*)d_in[3];
  const float* qw   = (const float*)d_in[4];
  const float* kw   = (const float*)d_in[5];
  const float* wo   = (const float*)d_in[6];
  float* out = (float*)d_out;

  u16* ws      = (u16*)d_ws;
  u16* hs_bf   = ws;                       // 6291456 elems
  u16* wqkv_bf = hs_bf + 6291456;          // 6291456
  u16* wo_bf   = wqkv_bf + 6291456;        // 4194304
  u16* qkv     = wo_bf + 4194304;          // 9437184 (V region unused)
  u16* vt      = qkv + 9437184;            // 1572864  (V^T: [4*128][3072])
  u16* attn    = hs_bf;                    // reuse (hs_bf dead after GEMM1)

  k_cvt3<<<2560, 256, 0, stream>>>(hs, hs_bf, T_TOK * HID,
                                   wqkv, wqkv_bf, QKVN * HID,
                                   wo, wo_bf, HID * HID);
  // GEMM1: 3072x3072x2048, BM=BN=192 -> 16x16 = 256 blocks (1/CU, no tail)
  k_gemm2p<6, 3, true, true><<<dim3(16, 16), 512, 0, stream>>>(hs_bf, wqkv_bf, qkv, vt,
                                                               T_TOK, QKVN, HID);
  k_normropeK<<<dim3(T_TOK), 256, 0, stream>>>(qkv, cs, sn, kw);
  k_attn<<<768, 256, 0, stream>>>(qkv, vt, cs, sn, qw, attn);
  // GEMM2: 3072x2048x2048, BM=192 BN=128 -> 16x16 = 256 blocks
  k_gemm2p<6, 2, false, false><<<dim3(16, 16), 512, 0, stream>>>(attn, wo_bf, out, nullptr,
                                                                 T_TOK, HID, HID);
}

// Round 18
// 150.980 us; speedup vs baseline: 1.4376x; 1.0007x over previous
//
#include <hip/hip_runtime.h>

typedef unsigned short u16;
typedef unsigned int u32;
typedef __attribute__((ext_vector_type(8))) short bf16x8;
typedef __attribute__((ext_vector_type(4))) float f32x4;
typedef __attribute__((ext_vector_type(4))) u32 u32x4;

#define T_TOK 3072
#define HID 2048
#define NH 16
#define NKV 4
#define HD 128
#define QKVN 3072
#define ATT_SCALE 0.08838834764831845f
#define LOG2E 1.4426950408889634f
#define SCL2 (ATT_SCALE * LOG2E)

__device__ __forceinline__ u16 f2bf(float x) {
  u32 u = __builtin_bit_cast(u32, x);
  u = u + 0x7FFFu + ((u >> 16) & 1u);
  return (u16)(u >> 16);
}
__device__ __forceinline__ float bf2f(u16 h) {
  return __builtin_bit_cast(float, (u32)h << 16);
}
__device__ __forceinline__ u32 cvtpk(float lo, float hi) {
  u32 r;
  asm("v_cvt_pk_bf16_f32 %0, %1, %2" : "=v"(r) : "v"(lo), "v"(hi));
  return r;
}
__device__ __forceinline__ void gload16(const void* g, void* l) {
  __builtin_amdgcn_global_load_lds((const __attribute__((address_space(1))) void*)g,
                                   (__attribute__((address_space(3))) void*)l, 16, 0, 0);
}

// ---------------- fp32 -> bf16 convert, 5 regions in one launch ----------------
__global__ void k_cvt5(const float* __restrict__ s0p, u16* __restrict__ d0p, int n0,
                       const float* __restrict__ s1p, u16* __restrict__ d1p, int n1,
                       const float* __restrict__ s2p, u16* __restrict__ d2p, int n2,
                       const float* __restrict__ s3p, u16* __restrict__ d3p, int n3,
                       const float* __restrict__ s4p, u16* __restrict__ d4p, int n4) {
  const float* s;
  u16* d;
  int n, b = blockIdx.x, nb;
  if (b < 1024) {
    s = s0p; d = d0p; n = n0; nb = 1024;
  } else if (b < 2048) {
    s = s1p; d = d1p; n = n1; b -= 1024; nb = 1024;
  } else if (b < 2560) {
    s = s2p; d = d2p; n = n2; b -= 2048; nb = 512;
  } else if (b < 2752) {
    s = s3p; d = d3p; n = n3; b -= 2560; nb = 192;
  } else {
    s = s4p; d = d4p; n = n4; b -= 2752; nb = 192;
  }
  int i = (b * 256 + threadIdx.x) * 4;
  int stride = nb * 256 * 4;
  for (; i < n; i += stride) {
    float4 v = *(const float4*)(s + i);
    u32 lo = cvtpk(v.x, v.y);
    u32 hi = cvtpk(v.z, v.w);
    *(uint2*)(d + i) = make_uint2(lo, hi);
  }
}

// ---------------- 2-phase double-buffered GEMM: C = A * B^T ----------------
// (round-12 configuration — measured 42/28 µs)
template <int MR, int NR, bool OUT_BF16, bool VT_MODE>
__global__ __launch_bounds__(512) void k_gemm2p(const u16* __restrict__ A,
                                                const u16* __restrict__ B,
                                                void* __restrict__ Cp,
                                                u16* __restrict__ vt,
                                                int M, int N, int K) {
  constexpr int BM = 32 * MR;
  constexpr int BN = 64 * NR;
  __shared__ u16 Ash[2][BM * 64];
  __shared__ u16 Bsh[2][BN * 64];
  const int tid = threadIdx.x;
  const int wv = tid >> 6, ln = tid & 63;
  const int wr = wv >> 2, wc = wv & 3;
  const int g = ln >> 4, r16 = ln & 15;
  const int m0 = blockIdx.y * BM, n0 = blockIdx.x * BN;
  const int NT = K >> 6;
  const int srow = ln >> 3;                   // row within 8-row DMA block
  const int sswz = ((ln & 7) ^ srow) << 3;    // pre-swizzled source col (elems)
  const u16* Abase = A + (size_t)m0 * K;
  const u16* Bbase = B + (size_t)n0 * K;
  const int xorc = (r16 & 7) << 3;

  f32x4 acc[MR][NR] = {};

  auto stage = [&](int buf, int T) {
#pragma unroll
    for (int a = 0; a < BM / 64; ++a)
      gload16(Abase + (size_t)(a * 64 + wv * 8 + srow) * K + T * 64 + sswz,
              &Ash[buf][(a * 64 + wv * 8) * 64]);
#pragma unroll
    for (int b = 0; b < BN / 64; ++b)
      gload16(Bbase + (size_t)(b * 64 + wv * 8 + srow) * K + T * 64 + sswz,
              &Bsh[buf][(b * 64 + wv * 8) * 64]);
  };

  stage(0, 0);
  __syncthreads();
  int cur = 0;
  for (int T = 0; T < NT; ++T) {
    if (T + 1 < NT) stage(cur ^ 1, T + 1);
    const u16* As = Ash[cur];
    const u16* Bs = Bsh[cur];
#pragma unroll
    for (int kk = 0; kk < 2; ++kk) {
      const int ecol = (kk * 32 + g * 8) ^ xorc;
      bf16x8 af[MR], bfr[NR];
#pragma unroll
      for (int m = 0; m < MR; ++m)
        af[m] = *(const bf16x8*)&As[(wr * (MR * 16) + m * 16 + r16) * 64 + ecol];
#pragma unroll
      for (int n = 0; n < NR; ++n)
        bfr[n] = *(const bf16x8*)&Bs[(wc * (NR * 16) + n * 16 + r16) * 64 + ecol];
      __builtin_amdgcn_s_setprio(1);
#pragma unroll
      for (int m = 0; m < MR; ++m)
#pragma unroll
        for (int n = 0; n < NR; ++n)
          acc[m][n] = __builtin_amdgcn_mfma_f32_16x16x32_bf16(af[m], bfr[n], acc[m][n], 0, 0, 0);
      __builtin_amdgcn_s_setprio(0);
    }
    __syncthreads();
    cur ^= 1;
  }
  // ---- epilogue ----
#pragma unroll
  for (int n = 0; n < NR; ++n) {
    int col = n0 + wc * (NR * 16) + n * 16 + r16;
    bool tov = VT_MODE && (col >= 2560);
#pragma unroll
    for (int m = 0; m < MR; ++m) {
      int row = m0 + wr * (MR * 16) + m * 16 + g * 4;
      if (tov) {
        u32 lo2 = (u32)f2bf(acc[m][n][0]) | ((u32)f2bf(acc[m][n][1]) << 16);
        u32 hi2 = (u32)f2bf(acc[m][n][2]) | ((u32)f2bf(acc[m][n][3]) << 16);
        *(uint2*)&vt[(size_t)(col - 2560) * T_TOK + row] = make_uint2(lo2, hi2);
      } else {
#pragma unroll
        for (int j = 0; j < 4; ++j) {
          if (OUT_BF16)
            ((u16*)Cp)[(size_t)(row + j) * N + col] = f2bf(acc[m][n][j]);
          else
            ((float*)Cp)[(size_t)(row + j) * N + col] = acc[m][n][j];
        }
      }
    }
  }
}

// ---------------- RMSNorm + RoPE for K heads only (bf16 cos/sin table) ----------------
__global__ void k_normropeK(u16* __restrict__ qkv, const u16* __restrict__ csb,
                            const u16* __restrict__ snb, const float* __restrict__ kw) {
  int t = blockIdx.x;
  int kh = threadIdx.x >> 6;      // 0..3
  int l = threadIdx.x & 63;
  u16* p = qkv + (size_t)t * QKVN + HID + kh * HD;
  float x0 = bf2f(p[l]), x1 = bf2f(p[l + 64]);
  float ss = x0 * x0 + x1 * x1;
#pragma unroll
  for (int d = 1; d < 64; d <<= 1) ss += __shfl_xor(ss, d, 64);
  float rs = rsqrtf(ss * (1.0f / 128.0f) + 1e-6f);
  float xn0 = x0 * rs * kw[l];
  float xn1 = x1 * rs * kw[l + 64];
  const u16* ct = csb + (size_t)t * HD;
  const u16* st = snb + (size_t)t * HD;
  float o0 = xn0 * bf2f(ct[l]) - xn1 * bf2f(st[l]);
  float o1 = xn1 * bf2f(ct[l + 64]) + xn0 * bf2f(st[l + 64]);
  p[l] = f2bf(o0);
  p[l + 64] = f2bf(o1);
}

// ---------------- GQA attention: swapped-QK in-reg softmax, DMA-staged LDS ----------------
// Round-17 kernel with bf16 cos/sin table for the fused Q-prep (half the
// table loads and bytes).
__global__ __launch_bounds__(256, 4) void k_attn(const u16* __restrict__ qkv,
                                                 const u16* __restrict__ vt,
                                                 const u16* __restrict__ csb,
                                                 const u16* __restrict__ snb,
                                                 const float* __restrict__ qw,
                                                 u16* __restrict__ attn) {
  __shared__ u16 Ksh[64 * 128];     // [s][granule ^ (s&7)]
  __shared__ u16 Vsh[128 * 64];     // [d][granule ^ (d&7)]
  const int id = blockIdx.x;
  const int xcd = id & 7, slot = id >> 3;              // slot 0..95
  const int hkv = xcd >> 1;                            // 2 XCDs per kv-group
  const int t0 = (191 - (slot * 2 + (xcd & 1))) * 16;  // reversed: long blocks first
  const int tid = threadIdx.x, wv = tid >> 6, ln = tid & 63;
  const int g = ln >> 4, r16 = ln & 15;
  const int h = hkv * 4 + wv;
  const int swz = r16 & 7;
  const bool ghi = (g >> 1) != 0;
  const int L0 = r16 + 16 * ((2 * g) & 3);   // src lanes for P-fragment shfl
  const int L1 = r16 + 16 * ((2 * g + 1) & 3);

  // ---- one-time: load raw Q, RMSNorm + RoPE in fp32, pack to bf16 fragments ----
  bf16x8 qf[4];
  {
    const u16* qrow = qkv + (size_t)(t0 + r16) * QKVN + h * HD;
    float xn[4][8];
    float ss = 0.f;
#pragma unroll
    for (int kk = 0; kk < 4; ++kk) {
      bf16x8 v = *(const bf16x8*)(qrow + kk * 32 + g * 8);
#pragma unroll
      for (int e = 0; e < 8; ++e) {
        float x = bf2f((u16)v[e]);
        xn[kk][e] = x;
        ss = fmaf(x, x, ss);
      }
    }
    ss += __shfl_xor(ss, 16, 64);
    ss += __shfl_xor(ss, 32, 64);
    float rs = rsqrtf(ss * (1.0f / 128.0f) + 1e-6f);
#pragma unroll
    for (int kk = 0; kk < 4; ++kk) {
      const int d0 = kk * 32 + g * 8;
      float4 w0v = *(const float4*)(qw + d0);
      float4 w1v = *(const float4*)(qw + d0 + 4);
#pragma unroll
      for (int e = 0; e < 4; ++e) xn[kk][e] *= rs * (&w0v.x)[e];
#pragma unroll
      for (int e = 0; e < 4; ++e) xn[kk][4 + e] *= rs * (&w1v.x)[e];
    }
    const u16* ct = csb + (size_t)(t0 + r16) * HD;
    const u16* st = snb + (size_t)(t0 + r16) * HD;
#pragma unroll
    for (int kk = 0; kk < 4; ++kk) {
      const int d0 = kk * 32 + g * 8;
      bf16x8 cv = *(const bf16x8*)(ct + d0);
      bf16x8 sv8 = *(const bf16x8*)(st + d0);
      float o[8];
#pragma unroll
      for (int e = 0; e < 8; ++e) {
        float cc = bf2f((u16)cv[e]);
        float sv = bf2f((u16)sv8[e]);
        float a = xn[kk][e];
        float b = (kk < 2) ? xn[kk + 2][e] : xn[kk - 2][e];
        o[e] = (kk < 2) ? (a * cc - b * sv) : fmaf(a, cc, b * sv);
      }
      u32x4 pk;
#pragma unroll
      for (int q = 0; q < 4; ++q) pk[q] = cvtpk(o[2 * q], o[2 * q + 1]);
      qf[kk] = __builtin_bit_cast(bf16x8, pk);
    }
  }

  float m_run = -1e30f, l_part = 0.f;   // row t = t0 + r16 (per-lane)
  f32x4 acc_o[8] = {};                  // rows t = t0 + g*4+j, cols d = db*16+r16

  const u16* Kbase = qkv + HID + hkv * HD;
  const u16* Vbase = vt + (size_t)(hkv * HD) * T_TOK;

  int lo = t0 - 1023;
  if (lo < 0) lo = 0;
  lo &= ~63;
  const int t_hi = t0 + 15;

  for (int s0 = lo; s0 <= t_hi; s0 += 64) {
    // ---- stage K [64][128] + V^T [128][64] via global_load_lds ----
#pragma unroll
    for (int ph = 0; ph < 4; ++ph) {
      int ks = wv * 16 + ph * 4 + (ln >> 4);
      int kc = (ln & 15) ^ (ks & 7);
      gload16(Kbase + (size_t)(s0 + ks) * QKVN + (kc << 3),
              &Ksh[(wv * 16 + ph * 4) * 128]);
      int vd = wv * 32 + ph * 8 + (ln >> 3);
      int vc = (ln & 7) ^ (vd & 7);
      gload16(Vbase + (size_t)vd * T_TOK + s0 + (vc << 3),
              &Vsh[(wv * 32 + ph * 8) * 64]);
    }
    __syncthreads();  // drains vmcnt(0): staged data visible

    // ---- S^T = K Q^T (swapped): sc[sb] rows s_local=g*4+j, cols t=r16 ----
    f32x4 sc[4] = {};
    __builtin_amdgcn_s_setprio(1);
#pragma unroll
    for (int sb = 0; sb < 4; ++sb) {
#pragma unroll
      for (int kk = 0; kk < 4; ++kk) {
        const bf16x8 kf =
            *(const bf16x8*)&Ksh[(sb * 16 + r16) * 128 + (((kk * 4 + g) ^ swz) << 3)];
        sc[sb] = __builtin_amdgcn_mfma_f32_16x16x32_bf16(kf, qf[kk], sc[sb], 0, 0, 0);
      }
    }
    __builtin_amdgcn_s_setprio(0);

    // ---- mask (specialized: only last tile + window tile) + row max ----
    const bool mtile = (s0 > t0 - 60) || (t0 >= 1024 && s0 == lo);
    const int t = t0 + r16;
    float pmax = -__builtin_inff();
    if (mtile) {
#pragma unroll
      for (int sb = 0; sb < 4; ++sb)
#pragma unroll
        for (int j = 0; j < 4; ++j) {
          int s = s0 + sb * 16 + g * 4 + j;
          bool ok = (s <= (t | 3)) && (t - s < 1024);
          float x = ok ? sc[sb][j] : -__builtin_inff();
          sc[sb][j] = x;
          pmax = fmaxf(pmax, x);
        }
    } else {
#pragma unroll
      for (int sb = 0; sb < 4; ++sb)
#pragma unroll
        for (int j = 0; j < 4; ++j) pmax = fmaxf(pmax, sc[sb][j]);
    }
    pmax = fmaxf(pmax, __shfl_xor(pmax, 16, 64));
    pmax = fmaxf(pmax, __shfl_xor(pmax, 32, 64));

    // ---- defer-max online softmax (log2 domain) ----
    float needv = fmaf(pmax, SCL2, -m_run);
    if (!__all(needv <= 11.5f)) {
      float mnew = fmaxf(m_run, pmax * SCL2);
      float fac = exp2f(m_run - mnew);
      m_run = mnew;
      l_part *= fac;
      float fj[4];
#pragma unroll
      for (int j = 0; j < 4; ++j) fj[j] = __shfl(fac, (ln & 48) + g * 4 + j, 64);
#pragma unroll
      for (int db = 0; db < 8; ++db)
#pragma unroll
        for (int j = 0; j < 4; ++j) acc_o[db][j] *= fj[j];
    }
    const float nm = -m_run;
    u32 w0[4], w1[4];
#pragma unroll
    for (int sb = 0; sb < 4; ++sb) {
      float e0 = exp2f(fmaf(sc[sb][0], SCL2, nm));
      float e1 = exp2f(fmaf(sc[sb][1], SCL2, nm));
      float e2 = exp2f(fmaf(sc[sb][2], SCL2, nm));
      float e3 = exp2f(fmaf(sc[sb][3], SCL2, nm));
      l_part += (e0 + e1) + (e2 + e3);
      w0[sb] = cvtpk(e0, e1);
      w1[sb] = cvtpk(e2, e3);
    }

    // ---- O += P V: P rearranged lane->A-fragment via shfl (no LDS) ----
    __builtin_amdgcn_s_setprio(1);
#pragma unroll
    for (int s32 = 0; s32 < 2; ++s32) {
      u32 a0 = __shfl(w0[2 * s32], L0, 64), b0 = __shfl(w0[2 * s32 + 1], L0, 64);
      u32 a1 = __shfl(w1[2 * s32], L0, 64), b1 = __shfl(w1[2 * s32 + 1], L0, 64);
      u32 a2 = __shfl(w0[2 * s32], L1, 64), b2 = __shfl(w0[2 * s32 + 1], L1, 64);
      u32 a3 = __shfl(w1[2 * s32], L1, 64), b3 = __shfl(w1[2 * s32 + 1], L1, 64);
      u32x4 pw;
      pw[0] = ghi ? b0 : a0;
      pw[1] = ghi ? b1 : a1;
      pw[2] = ghi ? b2 : a2;
      pw[3] = ghi ? b3 : a3;
      const bf16x8 pa = __builtin_bit_cast(bf16x8, pw);
#pragma unroll
      for (int db = 0; db < 8; ++db) {
        const bf16x8 vb =
            *(const bf16x8*)&Vsh[(db * 16 + r16) * 64 + (((s32 * 4 + g) ^ swz) << 3)];
        acc_o[db] = __builtin_amdgcn_mfma_f32_16x16x32_bf16(pa, vb, acc_o[db], 0, 0, 0);
      }
    }
    __builtin_amdgcn_s_setprio(0);
    __syncthreads();  // all waves done reading before next tile's DMA lands
  }

  // ---- epilogue: finalize l (cross-group), broadcast to acc layout ----
  float lt = l_part + __shfl_xor(l_part, 16, 64);
  lt = lt + __shfl_xor(lt, 32, 64);
  float inv = 1.0f / lt;
  float ij[4];
#pragma unroll
  for (int j = 0; j < 4; ++j) ij[j] = __shfl(inv, (ln & 48) + g * 4 + j, 64);
#pragma unroll
  for (int j = 0; j < 4; ++j) {
    int tt = t0 + g * 4 + j;
    u16* orow = attn + (size_t)tt * HID + h * HD;
#pragma unroll
    for (int db = 0; db < 8; ++db) orow[db * 16 + r16] = f2bf(acc_o[db][j] * ij[j]);
  }
}

extern "C" void kernel_launch(void* const* d_in, const int* in_sizes, int n_in,
                              void* d_out, int out_size, void* d_ws, size_t ws_size,
                              hipStream_t stream) {
  const float* hs   = (const float*)d_in[0];
  const float* cs   = (const float*)d_in[1];
  const float* sn   = (const float*)d_in[2];
  const float* wqkv = (const float*)d_in[3];
  const float* qw   = (const float*)d_in[4];
  const float* kw   = (const float*)d_in[5];
  const float* wo   = (const float*)d_in[6];
  float* out = (float*)d_out;

  u16* ws      = (u16*)d_ws;
  u16* hs_bf   = ws;                       // 6291456 elems
  u16* wqkv_bf = hs_bf + 6291456;          // 6291456
  u16* wo_bf   = wqkv_bf + 6291456;        // 4194304
  u16* qkv     = wo_bf + 4194304;          // 9437184 (V region unused)
  u16* vt      = qkv + 9437184;            // 1572864  (V^T: [4*128][3072])
  u16* csb     = vt + 1572864;             // 393216  (bf16 cos table)
  u16* snb     = csb + 393216;             // 393216  (bf16 sin table)
  u16* attn    = hs_bf;                    // reuse (hs_bf dead after GEMM1)

  k_cvt5<<<2944, 256, 0, stream>>>(hs, hs_bf, T_TOK * HID,
                                   wqkv, wqkv_bf, QKVN * HID,
                                   wo, wo_bf, HID * HID,
                                   cs, csb, T_TOK * HD,
                                   sn, snb, T_TOK * HD);
  // GEMM1: 3072x3072x2048, BM=BN=192 -> 16x16 = 256 blocks (1/CU, no tail)
  k_gemm2p<6, 3, true, true><<<dim3(16, 16), 512, 0, stream>>>(hs_bf, wqkv_bf, qkv, vt,
                                                               T_TOK, QKVN, HID);
  k_normropeK<<<dim3(T_TOK), 256, 0, stream>>>(qkv, csb, snb, kw);
  k_attn<<<768, 256, 0, stream>>>(qkv, vt, csb, snb, qw, attn);
  // GEMM2: 3072x2048x2048, BM=192 BN=128 -> 16x16 = 256 blocks
  k_gemm2p<6, 2, false, false><<<dim3(16, 16), 512, 0, stream>>>(attn, wo_bf, out, nullptr,
                                                                 T_TOK, HID, HID);
}